// Round 4
// baseline (103.658 us; speedup 1.0000x reference)
//
#include <hip/hip_runtime.h>

// RandomRectangleErasing, fp32, B=64,C=3,H=512,W=512.
// R1 75.6us / R2 81.8 / R3 78.9 — hand-rolled copy+mask kernels all plateau
// at ~5.3 TB/s. New approach: bulk hipMemcpyAsync D2D (AMD-tuned blit path,
// ~85% peak per rocprof.md) + a tiny kernel that zeroes only the erased rect
// (~4.6% of pixels, ~9 MB of writes).

constexpr int Bc = 64, Cc = 3, Hc = 512, Wc = 512;

__global__ __launch_bounds__(256) void zero_rect_kernel(
    float* __restrict__ out,
    const int* __restrict__ xs, const int* __restrict__ ys,
    const int* __restrict__ wd, const int* __restrict__ ht)
{
    // one block per (b, c) image plane: 192 blocks
    const int img = blockIdx.x;
    const int b   = img / 3;

    const int x0 = xs[b];
    const int y0 = ys[b];
    const int x1 = min(x0 + wd[b], Wc);   // rect may extend past image edge
    const int y1 = min(y0 + ht[b], Hc);
    const int rw = x1 - x0;
    const int rh = y1 - y0;
    if (rw <= 0 || rh <= 0) return;

    float* base = out + (size_t)img * (Hc * Wc);

    // lanes 0..rw-1 write one contiguous row segment each iteration (coalesced)
    for (int r = 0; r < rh; ++r) {
        float* rowp = base + (y0 + r) * Wc + x0;
        for (int c = threadIdx.x; c < rw; c += 256) {
            rowp[c] = 0.f;
        }
    }
}

extern "C" void kernel_launch(void* const* d_in, const int* in_sizes, int n_in,
                              void* d_out, int out_size, void* d_ws, size_t ws_size,
                              hipStream_t stream) {
    const float* in  = (const float*)d_in[0];
    const int*   wd  = (const int*)d_in[1];
    const int*   ht  = (const int*)d_in[2];
    const int*   xs  = (const int*)d_in[3];
    const int*   ys  = (const int*)d_in[4];
    float*       out = (float*)d_out;

    // bulk copy: 64*3*512*512 * 4B = 201.3 MB on the tuned D2D path
    hipMemcpyAsync(out, in, (size_t)out_size * sizeof(float),
                   hipMemcpyDeviceToDevice, stream);

    // then zero the erased rectangles (tiny, ~9 MB of writes)
    zero_rect_kernel<<<Bc * Cc, 256, 0, stream>>>(out, xs, ys, wd, ht);
}

// Round 6
// 61.356 us; speedup vs baseline: 1.6895x; 1.6895x over previous
//
#include <hip/hip_runtime.h>

// RandomRectangleErasing, fp32, B=64,C=3,H=512,W=512.
// R1 75.6us (grid-stride, predicated, rect load-skip)  <- best
// R2 81.8 / R3 78.9 / R4 103.7                         REGRESSED
// R5: compile fail (__builtin_nontemporal_store needs native vector type)
// R6: R1 body + nt stores via ext_vector_type(4) float. Input (201MB) fits
// 256MB L3; nt stores keep the write stream from evicting it, so timed
// replays read from L3 instead of HBM.

typedef float f32x4 __attribute__((ext_vector_type(4)));

constexpr int Hc = 512, Wc = 512;
constexpr int VPR   = Wc / 4;                  // 128 float4 per row
constexpr int TOTAL = 64 * 3 * Hc * VPR;       // 12,582,912 float4

__global__ __launch_bounds__(256) void erase_kernel(
    const f32x4* __restrict__ in, f32x4* __restrict__ out,
    const int* __restrict__ xs, const int* __restrict__ ys,
    const int* __restrict__ wd, const int* __restrict__ ht)
{
    const int stride = gridDim.x * blockDim.x;
    for (int idx = blockIdx.x * blockDim.x + threadIdx.x; idx < TOTAL;
         idx += stride) {
        const int img = idx >> 16;             // 65536 float4 per (b,c) plane
        const int b   = img / 3;               // magic-mul
        const int h   = (idx >> 7) & (Hc - 1);
        const int w   = (idx & (VPR - 1)) << 2;

        const int x0 = xs[b];
        const int y0 = ys[b];
        const int x1 = x0 + wd[b];
        const int y1 = y0 + ht[b];

        const bool in_row = (h >= y0) && (h < y1);

        f32x4 v;
        if (in_row && (w >= x0) && (w + 4 <= x1)) {
            v = (f32x4){0.f, 0.f, 0.f, 0.f};       // fully erased: skip load
        } else {
            v = in[idx];                           // normal load -> L3-allocates
            if (in_row) {
                if (w + 0 >= x0 && w + 0 < x1) v.x = 0.f;
                if (w + 1 >= x0 && w + 1 < x1) v.y = 0.f;
                if (w + 2 >= x0 && w + 2 < x1) v.z = 0.f;
                if (w + 3 >= x0 && w + 3 < x1) v.w = 0.f;
            }
        }
        __builtin_nontemporal_store(v, &out[idx]); // nt: don't evict input from L3
    }
}

extern "C" void kernel_launch(void* const* d_in, const int* in_sizes, int n_in,
                              void* d_out, int out_size, void* d_ws, size_t ws_size,
                              hipStream_t stream) {
    const f32x4* in  = (const f32x4*)d_in[0];
    const int*   wd  = (const int*)d_in[1];
    const int*   ht  = (const int*)d_in[2];
    const int*   xs  = (const int*)d_in[3];
    const int*   ys  = (const int*)d_in[4];
    f32x4*       out = (f32x4*)d_out;

    erase_kernel<<<2048, 256, 0, stream>>>(in, out, xs, ys, wd, ht);
}